// Round 16
// baseline (285.014 us; speedup 1.0000x reference)
//
#include <hip/hip_runtime.h>

typedef _Float16 half8 __attribute__((ext_vector_type(8)));
typedef float f32x4 __attribute__((ext_vector_type(4)));
typedef unsigned long long u64;

#define SPH  32           // timesteps per phase
#define XSW  32           // xs row stride (floats)
#define C2W  48           // c2L row stride (floats); wave m=2 writes cols 32..47
#define TN   1000

// R16 = R5 fused pipeline + ballot bit-packed spikes (R13-15 validated) +
// R12's T-split (numerically validated: absmax identical with 128-step burn-in).
// LDS 24.6 KB (was 70.7 KB > 64 KB -- the suspected reason R12's 2-blocks/CU
// co-residency failed). 512 blocks = 256 b x 2 T-chunks, 2 blocks/CU.
// Per iteration ph (ONE barrier):
//   waves 0-2: conv+LIF1(ph): thread ct owns neurons 2ct,2ct+1; spikes exported
//              as 2 ballots -> lane0 writes ulonglong2 to spkb[ph&1][s] (48B/t).
//   waves 3-5: FC GEMM(ph-1): read 2x48B bit-rows, unpack per-kt in registers
//              (grp = kt>>2 compile-time; shift = (kt&3)*16+q*4), 24 MFMA.
//   wave 3:    LIF2 scan(ph-2), loads hoisted before GEMM.
__global__ __launch_bounds__(384, 3) void snn_fwd(
    const float* __restrict__ x,      // (256,1000,30)
    const float* __restrict__ conv_w, // (16,1,7)
    const float* __restrict__ conv_b, // (16)
    const float* __restrict__ fc_w,   // (35,384)
    const float* __restrict__ fc_b,   // (35)
    float* __restrict__ out)          // (256,35)
{
    __shared__ unsigned spkb[2][SPH][16];   //  4096 B (12 u32 used + 4 pad per t)
    __shared__ float    xs[2][SPH][XSW];    //  8192 B
    __shared__ float    c2L[2][SPH][C2W];   // 12288 B  -> 24576 B total

    const int tid  = threadIdx.x;
    const int blk  = blockIdx.x;
    const int b    = blk & 255;
    const int chunk= blk >> 8;
    const int wid  = tid >> 6;
    const int lane = tid & 63;

    const int s0    = chunk ? 416 : 0;     // first computed timestep
    const int nPh   = chunk ? 19  : 17;    // compute phases (x32 steps)
    const int accLo = chunk ? 544 : 0;     // accumulate [accLo, accHi)
    const int accHi = chunk ? TN  : 544;
    const int NITb  = nPh + 2;

    // ---------- conv-wave setup: thread ct -> (c=ct/12, u=ct%12), neurons 2ct,2ct+1 ----------
    const int ct = tid;          // 0..191 when wid<3
    const int c  = ct / 12;
    const int u  = ct % 12;
    float wk[7];
    float cb = 0.f;
    if (wid < 3) {
#pragma unroll
        for (int k = 0; k < 7; ++k) wk[k] = conv_w[c * 7 + k];
        cb = conv_b[c];
    }

    // ---------- FC-wave setup: A fragments (f16 weights, K=384) ----------
    const int m  = wid - 3;
    const int nL = lane & 15;    // B col (t_local); C col
    const int q  = lane >> 4;    // quad: k = q*8 + j
    half8 A[12];
    if (wid >= 3) {
        const int o = m * 16 + nL;
#pragma unroll
        for (int kt = 0; kt < 12; ++kt) {
            half8 a;
#pragma unroll
            for (int j = 0; j < 8; ++j) {
                int K = kt * 32 + q * 8 + j;
                a[j] = (o < 35) ? (_Float16)fc_w[o * 384 + K] : (_Float16)0.f;
            }
            A[kt] = a;
        }
    }
    const float fcb = (wid == 3 && lane < 35) ? fc_b[lane] : 0.f;

    // ---------- state (zero-init; chunk 1 uses 128-step burn-in, R12-validated) ----------
    float m10 = 0.f, m11 = 0.f, sp0 = 0.f, sp1 = 0.f;   // LIF1
    float mem2 = 0.f, accO = 0.f;                        // LIF2 (wave3 lanes<35)

    const float* xb = x + (size_t)b * (TN * 30);

    // ---------- prologue: stage xs[0] for phase 0 (t = s0..s0+31, all < TN) ----------
    if (wid < 3) {
#pragma unroll
        for (int r = 0; r < 5; ++r) {
            int f = ct + 192 * r;          // 0..959
            xs[0][f / 30][f % 30] = xb[(size_t)(s0 + f / 30) * 30 + (f % 30)];
        }
    }
    __syncthreads();

#pragma unroll 1
    for (int ph = 0; ph < NITb; ++ph) {
        if (wid < 3) {
            float xr[5];
            const bool stg = (ph <= nPh - 2);
            if (stg) {                     // bulk global loads for phase ph+1
                const float* src = xb + ((size_t)s0 + (ph + 1) * SPH) * 30;
#pragma unroll
                for (int r = 0; r < 5; ++r) {
                    int f = ct + 192 * r;
                    int t = s0 + (ph + 1) * SPH + f / 30;
                    xr[r] = (t < TN) ? src[f] : 0.f;
                }
            }
            if (ph < nPh) {
                const float* xrow = &xs[ph & 1][0][2 * u];
#pragma unroll 4
                for (int s = 0; s < SPH; ++s) {
                    const float2* x2 = (const float2*)(xrow + s * XSW);
                    float2 a0 = x2[0], a1 = x2[1], a2 = x2[2], a3 = x2[3];
                    float c1a = cb, c1b = cb;
                    c1a = fmaf(wk[0], a0.x, c1a);  c1b = fmaf(wk[0], a0.y, c1b);
                    c1a = fmaf(wk[1], a0.y, c1a);  c1b = fmaf(wk[1], a1.x, c1b);
                    c1a = fmaf(wk[2], a1.x, c1a);  c1b = fmaf(wk[2], a1.y, c1b);
                    c1a = fmaf(wk[3], a1.y, c1a);  c1b = fmaf(wk[3], a2.x, c1b);
                    c1a = fmaf(wk[4], a2.x, c1a);  c1b = fmaf(wk[4], a2.y, c1b);
                    c1a = fmaf(wk[5], a2.y, c1a);  c1b = fmaf(wk[5], a3.x, c1b);
                    c1a = fmaf(wk[6], a3.x, c1a);  c1b = fmaf(wk[6], a3.y, c1b);

                    m10 = fmaf(0.9f, m10, c1a - sp0);
                    m11 = fmaf(0.9f, m11, c1b - sp1);
                    sp0 = (m10 > 1.0f) ? 1.0f : 0.0f;
                    sp1 = (m11 > 1.0f) ? 1.0f : 0.0f;

                    u64 bal0 = __ballot(m10 > 1.0f);   // even neurons 128*wid+2L
                    u64 bal1 = __ballot(m11 > 1.0f);   // odd  neurons 128*wid+2L+1
                    if (lane == 0) {
                        ulonglong2 v; v.x = bal0; v.y = bal1;
                        *(ulonglong2*)&spkb[ph & 1][s][4 * wid] = v;
                    }
                }
            }
            if (stg) {
                float* dst = &xs[(ph + 1) & 1][0][0];
#pragma unroll
                for (int r = 0; r < 5; ++r) {
                    int f = ct + 192 * r;
                    dst[(f / 30) * XSW + (f % 30)] = xr[r];
                }
            }
        } else {
            // ---- scan loads hoisted before GEMM (wave 3) ----
            const bool doScan = (wid == 3 && lane < 35 && ph >= 2);
            float v[SPH];
            if (doScan) {
                const float* cs = &c2L[(ph - 2) & 1][0][0];
#pragma unroll
                for (int j = 0; j < SPH; ++j) v[j] = cs[j * C2W + lane];
            }
            if (ph >= 1 && ph <= nPh) {    // GEMM on spikes of phase ph-1
                const uint4* r0 = (const uint4*)&spkb[(ph - 1) & 1][nL][0];
                const uint4* r1 = (const uint4*)&spkb[(ph - 1) & 1][16 + nL][0];
                uint4 p0 = r0[0], p1 = r0[1], p2 = r0[2];
                uint4 q0 = r1[0], q1 = r1[1], q2 = r1[2];
                u64 E0[6], E1[6];
                E0[0] = p0.x | ((u64)p0.y << 32);  E0[1] = p0.z | ((u64)p0.w << 32);
                E0[2] = p1.x | ((u64)p1.y << 32);  E0[3] = p1.z | ((u64)p1.w << 32);
                E0[4] = p2.x | ((u64)p2.y << 32);  E0[5] = p2.z | ((u64)p2.w << 32);
                E1[0] = q0.x | ((u64)q0.y << 32);  E1[1] = q0.z | ((u64)q0.w << 32);
                E1[2] = q1.x | ((u64)q1.y << 32);  E1[3] = q1.z | ((u64)q1.w << 32);
                E1[4] = q2.x | ((u64)q2.y << 32);  E1[5] = q2.z | ((u64)q2.w << 32);

                f32x4 acc0 = {0.f, 0.f, 0.f, 0.f};
                f32x4 acc1 = {0.f, 0.f, 0.f, 0.f};
                const int shq = q * 4;
#pragma unroll
                for (int kt = 0; kt < 12; ++kt) {
                    const int g2 = (kt >> 2) * 2;          // compile-time group
                    const int sh = (kt & 3) * 16 + shq;    // runtime via q only
                    unsigned e0 = (unsigned)(E0[g2] >> sh) & 15u;
                    unsigned o0 = (unsigned)(E0[g2 + 1] >> sh) & 15u;
                    unsigned e1 = (unsigned)(E1[g2] >> sh) & 15u;
                    unsigned o1 = (unsigned)(E1[g2 + 1] >> sh) & 15u;
                    union { unsigned w[4]; half8 h; } B0, B1;
#pragma unroll
                    for (int jj = 0; jj < 4; ++jj) {
                        B0.w[jj] = (((e0 >> jj) & 1u) ? 0x3C00u : 0u) |
                                   (((o0 >> jj) & 1u) ? 0x3C000000u : 0u);
                        B1.w[jj] = (((e1 >> jj) & 1u) ? 0x3C00u : 0u) |
                                   (((o1 >> jj) & 1u) ? 0x3C000000u : 0u);
                    }
                    acc0 = __builtin_amdgcn_mfma_f32_16x16x32_f16(A[kt], B0.h, acc0, 0, 0, 0);
                    acc1 = __builtin_amdgcn_mfma_f32_16x16x32_f16(A[kt], B1.h, acc1, 0, 0, 0);
                }
                // C/D: col = lane&15 (t_local), row = q*4+i (o_local)
                float* cd = &c2L[(ph - 1) & 1][0][0];
                *(f32x4*)(cd + nL * C2W + m * 16 + q * 4)        = acc0;
                *(f32x4*)(cd + (16 + nL) * C2W + m * 16 + q * 4) = acc1;
            }
            if (doScan) {                  // LIF2 scan of phase ph-2
                const int tb = s0 + (ph - 2) * SPH;
#pragma unroll
                for (int j = 0; j < SPH; ++j) {
                    float r2 = (mem2 > 1.0f) ? 1.0f : 0.0f;
                    mem2 = 0.9f * mem2 + (v[j] + fcb) - r2;
                    int t = tb + j;
                    if (t >= accLo && t < accHi) accO += mem2;
                }
            }
        }
        __syncthreads();
    }

    if (wid == 3 && lane < 35)
        atomicAdd(&out[b * 35 + lane], accO * (1.0f / (float)TN));
}

extern "C" void kernel_launch(void* const* d_in, const int* in_sizes, int n_in,
                              void* d_out, int out_size, void* d_ws, size_t ws_size,
                              hipStream_t stream) {
    const float* x      = (const float*)d_in[0];
    const float* conv_w = (const float*)d_in[1];
    const float* conv_b = (const float*)d_in[2];
    const float* fc_w   = (const float*)d_in[3];
    const float* fc_b   = (const float*)d_in[4];
    float* out          = (float*)d_out;

    hipMemsetAsync(out, 0, (size_t)out_size * sizeof(float), stream);
    snn_fwd<<<512, 384, 0, stream>>>(x, conv_w, conv_b, fc_w, fc_b, out);
}